// Round 5
// baseline (258.331 us; speedup 1.0000x reference)
//
#include <hip/hip_runtime.h>

typedef __bf16 bf16;
typedef bf16 bf16x4 __attribute__((ext_vector_type(4)));
typedef bf16 bf16x8 __attribute__((ext_vector_type(8)));
typedef _Float16 half_t;
typedef half_t half4 __attribute__((ext_vector_type(4)));
typedef half_t half8 __attribute__((ext_vector_type(8)));
typedef float f32x4 __attribute__((ext_vector_type(4)));

#define NND 98      // landmarks
#define KNB 10      // neighbors per node
#define NH 4        // heads
#define CIN 256
#define HC 64
#define KAG 224     // aggregation GEMM K: rows 0..111 = h1, 112..223 = h0 (diag slot)
#define SROW 232    // S_T k-stride (224 + 8 pad): dword stride 116 -> conflict-free frag reads
#define XA_TILE (7 * 8 * 64 * 8)  // bf16 elems per batch item in xa

// workspace layout
#define WP_OFF   0
#define WP_BYTES 262144                       // 8*8*4*64*8 bf16
#define G2D_OFF  (WP_OFF + WP_BYTES)
#define G2D_BYTES (NH * 112 * KAG * 2)        // dense G2, f16: 200704
#define G2A_OFF  (G2D_OFF + G2D_BYTES)
#define G2A_BYTES (NH * 49 * 64 * 8 * 2)      // frag-packed G2, f16: 401408
#define XA_OFF   (G2A_OFF + G2A_BYTES)

// ---- misc1: blocks 0..63 pack Wp; blocks 64..67 build dense G2 (one head each) ----
// Wp[hs][kt(8)][nt(4)][lane(64)][8]: B[k=kt*32+(lane>>4)*8+j][n=nt*16+(lane&15)]
// G2d[h][i][j] (f16): A_off at j<112, diag[i] at j=112+i; rows>=98 zero.
__global__ __launch_bounds__(256) void misc1_kernel(const float* __restrict__ W,
                                                    bf16* __restrict__ Wp,
                                                    const float* __restrict__ e,
                                                    const int* __restrict__ cols,
                                                    half_t* __restrict__ G2d) {
  if (blockIdx.x < 64) {
    int t = blockIdx.x * 256 + threadIdx.x;
    int lane = t & 63;
    int nt = (t >> 6) & 3;
    int kt = (t >> 8) & 7;
    int hs = t >> 11;
    int n = nt * 16 + (lane & 15);
    int kb = kt * 32 + (lane >> 4) * 8;
    const float* src = W + (hs * CIN + kb) * HC + n;
    bf16x8 v;
#pragma unroll
    for (int j = 0; j < 8; ++j) v[j] = (bf16)src[j * HC];
    *(bf16x8*)(Wp + (long long)t * 8) = v;
    return;
  }
  const int h = blockIdx.x - 64;
  half_t* g = G2d + h * 112 * KAG;
  // zero 112*224 f16 = 12544 dwords
  for (int i = threadIdx.x; i < 112 * KAG / 2; i += 256) ((unsigned int*)g)[i] = 0u;
  __syncthreads();
  const int i = threadIdx.x;
  if (i < NND) {
    const int* cp = cols + i * KNB;
    const float* ep = e + (h * NND + i) * KNB;
    float ev[KNB];
    int cv[KNB];
    float mx = -3.0e38f;
#pragma unroll
    for (int j = 0; j < KNB; ++j) { cv[j] = cp[j]; ev[j] = ep[j]; mx = fmaxf(mx, ev[j]); }
    float s = 0.f;
#pragma unroll
    for (int j = 0; j < KNB; ++j) { ev[j] = __expf(ev[j] - mx); s += ev[j]; }
    const float inv = 1.f / s;
    float dg = 0.f;
#pragma unroll
    for (int j = 0; j < KNB; ++j) {
      float wj = ev[j] * inv;
      if (cv[j] == i) { dg = wj; wj = 0.f; }
      g[i * KAG + cv[j]] = (half_t)wj;   // A_off (diag slot gets 0 here, real diag below)
    }
    g[i * KAG + 112 + i] = (half_t)dg;
  }
}

// ---- misc2: blocks 0..48 pack G2a frags; blocks 49.. pack xa (one b per block, LDS-staged) ----
// G2a[h][mt(7)][kt(7)][lane(64)][8]: A[row=mt*16+(l&15)][k=kt*32+(l>>4)*8+j]
// xa[b][mt(7)][kt(8)][lane(64)][8]:  A[row=mt*16+(l&15)][k=kt*32+(l>>4)*8+j], rows>=98 zero
__global__ __launch_bounds__(256) void misc2_kernel(const half_t* __restrict__ G2d,
                                                    half_t* __restrict__ G2a,
                                                    const float* __restrict__ x,
                                                    bf16* __restrict__ xa, int B) {
  if (blockIdx.x < 49) {
    int t = blockIdx.x * 256 + threadIdx.x;  // 0..12543
    int lane = t & 63;
    int q = t >> 6;         // 0..195
    int kt = q % 7;
    int mt = (q / 7) % 7;
    int h = q / 49;
    int row = mt * 16 + (lane & 15);
    int k0 = kt * 32 + (lane >> 4) * 8;
    half8 v = *(const half8*)(G2d + (h * 112 + row) * KAG + k0);  // 16B aligned
    *(half8*)(G2a + (long long)t * 8) = v;
    return;
  }
  // xa pack: fully-coalesced reads -> LDS (XOR-swizzled) -> coalesced frag writes
  __shared__ __align__(16) bf16 xs[16 * 256];  // 8 KB, one 16-row M-tile
  const int b = blockIdx.x - 49;
  const int tid = threadIdx.x;
  const float* xb = x + (long long)b * NND * CIN;
  for (int mt = 0; mt < 7; ++mt) {
#pragma unroll
    for (int it = 0; it < 4; ++it) {
      int chunk = tid + it * 256;  // 0..1023: 16 rows x 64 f32x4 chunks
      int r = chunk >> 6;
      int c4 = chunk & 63;
      int g = mt * 16 + r;
      f32x4 v = {0.f, 0.f, 0.f, 0.f};
      if (g < NND) v = *(const f32x4*)(xb + g * CIN + c4 * 4);  // coalesced 1KB/row
      bf16x4 bv;
      bv[0] = (bf16)v[0]; bv[1] = (bf16)v[1]; bv[2] = (bf16)v[2]; bv[3] = (bf16)v[3];
      int byte = (r * 512 + c4 * 8) ^ ((r & 7) << 4);  // swizzled, conflict-free
      *(bf16x4*)((char*)xs + byte) = bv;
    }
    __syncthreads();
#pragma unroll
    for (int it = 0; it < 2; ++it) {
      int u = tid + it * 256;  // 0..511: 8 kt x 64 lanes
      int kt = u >> 6;
      int lane = u & 63;
      int r = lane & 15;
      int byte = (r * 512 + kt * 64 + (lane >> 4) * 16) ^ ((r & 7) << 4);
      bf16x8 f = *(const bf16x8*)((char*)xs + byte);  // conflict-free b128
      *(bf16x8*)(xa + ((((long long)b * 7 + mt) * 8 + kt) * 64 + lane) * 8) = f;  // coalesced
    }
    __syncthreads();
  }
}

// ---- main: one block per (batch-pair, head). 512 threads = 8 waves. ----
// GEMM1 (bf16): 2 x [112x256] @ [256x128] -> acc; acc -> S_T (f16, LDS, transposed+stacked)
// GEMM2 (f16):  out = G2[h] @ S  (M=112, N=64, K=224) + bias, masked store.
__global__ __launch_bounds__(512, 4) void semgconv_kernel(
    const bf16* __restrict__ xa, const half_t* __restrict__ G2a,
    const bf16* __restrict__ Wp, const float* __restrict__ bias,
    float* __restrict__ out, int nwg) {
  __shared__ __align__(16) half_t S[2][64 * SROW];  // 59392 B

  const int tid = threadIdx.x;
  const int lane = tid & 63;
  const int wv = tid >> 6;

  // XCD-chunked swizzle: 4 head-blocks of each pair land on one XCD.
  int n = blockIdx.x;
  int w = ((nwg & 7) == 0) ? ((n & 7) * (nwg >> 3) + (n >> 3)) : n;
  const int bp = w >> 2;
  const int h = w & 3;
  const int b0 = bp * 2;

  const int wm = wv & 3;   // M-group: tiles {2wm, 2wm+1}; wm=3 -> tile 6 only
  const int sh = wv >> 2;  // head-half: 0 -> h0, 1 -> h1
  const int mt0 = wm * 2;
  const bool has1 = (mt0 + 1 < 7);

  // ---- GEMM1 ----
  f32x4 acc[2][2][4] = {};  // [item][im][nt]
  {
    const bf16* wpl = Wp + ((long long)((h * 2 + sh) * 32) * 64 + lane) * 8;
    const bf16* ax0 = xa + (((long long)b0 * 7 + mt0) * 8 * 64 + lane) * 8;
    const bf16* ax1 = ax0 + XA_TILE;
#pragma unroll
    for (int kt = 0; kt < 8; ++kt) {
      bf16x8 a00 = *(const bf16x8*)(ax0 + kt * 512);
      bf16x8 a10 = *(const bf16x8*)(ax1 + kt * 512);
      bf16x8 a01 = {}, a11 = {};
      if (has1) {
        a01 = *(const bf16x8*)(ax0 + 4096 + kt * 512);
        a11 = *(const bf16x8*)(ax1 + 4096 + kt * 512);
      }
      bf16x8 bfr[4];
#pragma unroll
      for (int nt = 0; nt < 4; ++nt)
        bfr[nt] = *(const bf16x8*)(wpl + (long long)((kt * 4 + nt) * 64) * 8);
#pragma unroll
      for (int nt = 0; nt < 4; ++nt) {
        acc[0][0][nt] = __builtin_amdgcn_mfma_f32_16x16x32_bf16(a00, bfr[nt], acc[0][0][nt], 0, 0, 0);
        acc[1][0][nt] = __builtin_amdgcn_mfma_f32_16x16x32_bf16(a10, bfr[nt], acc[1][0][nt], 0, 0, 0);
      }
      if (has1) {
#pragma unroll
        for (int nt = 0; nt < 4; ++nt) {
          acc[0][1][nt] = __builtin_amdgcn_mfma_f32_16x16x32_bf16(a01, bfr[nt], acc[0][1][nt], 0, 0, 0);
          acc[1][1][nt] = __builtin_amdgcn_mfma_f32_16x16x32_bf16(a11, bfr[nt], acc[1][1][nt], 0, 0, 0);
        }
      }
    }
  }

  // ---- acc -> S_T: S[it][col][k], k = row (h1, sh=1) or 112+row (h0, sh=0) ----
  // C/D layout: col = nt*16 + (lane&15), rows = mt*16 + (lane>>4)*4 + r; the 4 r-values
  // are consecutive k in S_T -> one 8B ds_write_b64 each. 2-way banks (free).
  {
    const int jb = (sh ? 0 : 112) + (lane >> 4) * 4;
    const int cb = lane & 15;
#pragma unroll
    for (int it2 = 0; it2 < 2; ++it2) {
#pragma unroll
      for (int im = 0; im < 2; ++im) {
        if (mt0 + im < 7) {
          const int j0 = jb + (mt0 + im) * 16;
#pragma unroll
          for (int nt = 0; nt < 4; ++nt) {
            half4 hv;
            hv[0] = (half_t)acc[it2][im][nt][0];
            hv[1] = (half_t)acc[it2][im][nt][1];
            hv[2] = (half_t)acc[it2][im][nt][2];
            hv[3] = (half_t)acc[it2][im][nt][3];
            *(half4*)(&S[it2][(nt * 16 + cb) * SROW + j0]) = hv;
          }
        }
      }
    }
  }
  __syncthreads();  // S ready

  // ---- GEMM2: wave = (item, 16-col strip); 7 M-tiles x 7 K-steps ----
  const int it2 = wv & 1;
  const int nt2 = wv >> 1;  // 0..3
  f32x4 a2[7] = {};
  {
    const half_t* g2l = G2a + ((long long)h * 49 * 64 + lane) * 8;
    const half_t* sl = &S[it2][(nt2 * 16 + (lane & 15)) * SROW + (lane >> 4) * 8];
#pragma unroll
    for (int kt = 0; kt < 7; ++kt) {
      half8 bfr = *(const half8*)(sl + kt * 32);  // conflict-free b128
#pragma unroll
      for (int mt = 0; mt < 7; ++mt) {
        half8 afr = *(const half8*)(g2l + (long long)(mt * 7 + kt) * 64 * 8);
        a2[mt] = __builtin_amdgcn_mfma_f32_16x16x32_f16(afr, bfr, a2[mt], 0, 0, 0);
      }
    }
  }

  // ---- bias + masked store ----
  {
    const int col = nt2 * 16 + (lane & 15);
    const float bs = bias[h * HC + col];
    const int r0 = (lane >> 4) * 4;
    float* ob = out + (long long)(b0 + it2) * NND * (NH * HC) + h * HC + col;
#pragma unroll
    for (int mt = 0; mt < 7; ++mt) {
#pragma unroll
      for (int r = 0; r < 4; ++r) {
        const int row = mt * 16 + r0 + r;
        if (row < NND) ob[(long long)row * (NH * HC)] = a2[mt][r] + bs;
      }
    }
  }
}

extern "C" void kernel_launch(void* const* d_in, const int* in_sizes, int n_in,
                              void* d_out, int out_size, void* d_ws, size_t ws_size,
                              hipStream_t stream) {
  const float* x    = (const float*)d_in[0];
  const float* W    = (const float*)d_in[1];
  const float* e    = (const float*)d_in[2];
  const float* bias = (const float*)d_in[3];
  // d_in[4] = rows: unused (fixed pattern: row i owns edges i*K .. i*K+K-1)
  const int* cols   = (const int*)d_in[5];
  float* out        = (float*)d_out;

  int B = in_sizes[0] / (NND * CIN);  // 1024

  bf16* Wp    = (bf16*)((char*)d_ws + WP_OFF);
  half_t* G2d = (half_t*)((char*)d_ws + G2D_OFF);
  half_t* G2a = (half_t*)((char*)d_ws + G2A_OFF);
  bf16* xa    = (bf16*)((char*)d_ws + XA_OFF);
  // ws need: 262144 + 200704 + 401408 + B*57344 ~= 59.6 MB (round-2/4 proved >= 59.0 MB)

  misc1_kernel<<<68, 256, 0, stream>>>(W, Wp, e, cols, G2d);
  misc2_kernel<<<49 + B, 256, 0, stream>>>(G2d, G2a, x, xa, B);

  const int nwg = (B / 2) * NH;
  semgconv_kernel<<<nwg, 512, 0, stream>>>(xa, G2a, Wp, bias, out, nwg);
}

// Round 6
// 243.826 us; speedup vs baseline: 1.0595x; 1.0595x over previous
//
#include <hip/hip_runtime.h>

typedef __bf16 bf16;
typedef bf16 bf16x4 __attribute__((ext_vector_type(4)));
typedef bf16 bf16x8 __attribute__((ext_vector_type(8)));
typedef _Float16 half_t;
typedef half_t half4 __attribute__((ext_vector_type(4)));
typedef half_t half8 __attribute__((ext_vector_type(8)));
typedef float f32x4 __attribute__((ext_vector_type(4)));

#define NND 98      // landmarks
#define KNB 10      // neighbors per node
#define NH 4        // heads
#define CIN 256
#define HC 64
#define KAG 224     // aggregation GEMM K: 0..111 = h1, 112..223 = h0 (diag)
#define SROW 232    // S_T k-stride (224 + 8 pad)
#define XA_TILE (7 * 8 * 64 * 8)  // bf16 elems per batch item in xa

// workspace layout
#define WP_OFF   0
#define WP_BYTES 262144                       // 8*8*4*64*8 bf16
#define G2D_OFF  (WP_OFF + WP_BYTES)
#define G2D_BYTES (NH * 112 * KAG * 2)        // dense G2, f16
#define G2A_OFF  (G2D_OFF + G2D_BYTES)
#define G2A_BYTES (NH * 49 * 64 * 8 * 2)      // frag-packed G2, f16
#define XA_OFF   (G2A_OFF + G2A_BYTES)

__device__ __forceinline__ bf16x8 load_a8(const float* p) {
  f32x4 u = *(const f32x4*)p;
  f32x4 v = *(const f32x4*)(p + 4);
  bf16x8 a;
  a[0] = (bf16)u[0]; a[1] = (bf16)u[1]; a[2] = (bf16)u[2]; a[3] = (bf16)u[3];
  a[4] = (bf16)v[0]; a[5] = (bf16)v[1]; a[6] = (bf16)v[2]; a[7] = (bf16)v[3];
  return a;
}

// ---- misc1: blocks 0..63 pack Wp; blocks 64..67 build dense G2 (one head each) ----
__global__ __launch_bounds__(256) void misc1_kernel(const float* __restrict__ W,
                                                    bf16* __restrict__ Wp,
                                                    const float* __restrict__ e,
                                                    const int* __restrict__ cols,
                                                    half_t* __restrict__ G2d) {
  if (blockIdx.x < 64) {
    int t = blockIdx.x * 256 + threadIdx.x;
    int lane = t & 63;
    int nt = (t >> 6) & 3;
    int kt = (t >> 8) & 7;
    int hs = t >> 11;
    int n = nt * 16 + (lane & 15);
    int kb = kt * 32 + (lane >> 4) * 8;
    const float* src = W + (hs * CIN + kb) * HC + n;
    bf16x8 v;
#pragma unroll
    for (int j = 0; j < 8; ++j) v[j] = (bf16)src[j * HC];
    *(bf16x8*)(Wp + (long long)t * 8) = v;
    return;
  }
  const int h = blockIdx.x - 64;
  half_t* g = G2d + h * 112 * KAG;
  for (int i = threadIdx.x; i < 112 * KAG / 2; i += 256) ((unsigned int*)g)[i] = 0u;
  __syncthreads();
  const int i = threadIdx.x;
  if (i < NND) {
    const int* cp = cols + i * KNB;
    const float* ep = e + (h * NND + i) * KNB;
    float ev[KNB];
    int cv[KNB];
    float mx = -3.0e38f;
#pragma unroll
    for (int j = 0; j < KNB; ++j) { cv[j] = cp[j]; ev[j] = ep[j]; mx = fmaxf(mx, ev[j]); }
    float s = 0.f;
#pragma unroll
    for (int j = 0; j < KNB; ++j) { ev[j] = __expf(ev[j] - mx); s += ev[j]; }
    const float inv = 1.f / s;
    float dg = 0.f;
#pragma unroll
    for (int j = 0; j < KNB; ++j) {
      float wj = ev[j] * inv;
      if (cv[j] == i) { dg = wj; wj = 0.f; }
      g[i * KAG + cv[j]] = (half_t)wj;
    }
    g[i * KAG + 112 + i] = (half_t)dg;
  }
}

// ---- misc2: blocks 0..48 pack G2a frags; blocks 49.. pack xa (4 items/thread, ILP) ----
// G2a[h][mt(7)][kt(7)][lane(64)][8]; xa[b][mt(7)][kt(8)][lane(64)][8], rows>=98 zero
__global__ __launch_bounds__(256) void misc2_kernel(const half_t* __restrict__ G2d,
                                                    half_t* __restrict__ G2a,
                                                    const float* __restrict__ x,
                                                    bf16* __restrict__ xa, int B) {
  if (blockIdx.x < 49) {
    int t = blockIdx.x * 256 + threadIdx.x;  // 0..12543
    int lane = t & 63;
    int q = t >> 6;
    int kt = q % 7;
    int mt = (q / 7) % 7;
    int h = q / 49;
    int row = mt * 16 + (lane & 15);
    int k0 = kt * 32 + (lane >> 4) * 8;
    half8 v = *(const half8*)(G2d + (h * 112 + row) * KAG + k0);
    *(half8*)(G2a + (long long)t * 8) = v;
    return;
  }
  const int Bq = (B + 3) >> 2;
  int u = (blockIdx.x - 49) * 256 + threadIdx.x;  // (b0, mt, kt, lane), b0 < Bq
  if (u >= Bq * 7 * 8 * 64) return;
  const int lane = u & 63;
  const int kt = (u >> 6) & 7;
  const int v = u >> 9;
  const int b0 = v / 7;
  const int mt = v - b0 * 7;
  const int row = mt * 16 + (lane & 15);
  const int k0 = kt * 32 + (lane >> 4) * 8;
  bf16x8 a[4];
#pragma unroll
  for (int q = 0; q < 4; ++q) {
    const int b = b0 + Bq * q;
    a[q] = bf16x8{};
    if (b < B && row < NND) a[q] = load_a8(x + ((long long)b * NND + row) * CIN + k0);
  }
#pragma unroll
  for (int q = 0; q < 4; ++q) {
    const int b = b0 + Bq * q;
    if (b < B)
      *(bf16x8*)(xa + ((((long long)b * 7 + mt) * 8 + kt) * 64 + lane) * 8) = a[q];
  }
}

// ---- main: one block per (batch-pair, head). 512 threads = 8 waves. ----
// phase0: stage Wp-h (64KB) -> LDS (linear). GEMM1 (bf16): B from LDS, A from global xa.
// S_T (f16) overwrites the Wp LDS region. GEMM2 (f16): A = G2a (global, wave owns mt-pair),
// B = S from LDS. 3 barriers.
__global__ __launch_bounds__(512, 4) void semgconv_kernel(
    const bf16* __restrict__ xa, const half_t* __restrict__ G2a,
    const bf16* __restrict__ Wp, const float* __restrict__ bias,
    float* __restrict__ out, int nwg) {
  __shared__ __align__(16) unsigned char smem[65536];  // Wp-h stage, then S[2][64*SROW]
  bf16* Wl = (bf16*)smem;
  half_t* S = (half_t*)smem;

  const int tid = threadIdx.x;
  const int lane = tid & 63;
  const int wv = tid >> 6;

  // XCD-chunked swizzle: 4 head-blocks of each pair land on one XCD.
  int n = blockIdx.x;
  int w = ((nwg & 7) == 0) ? ((n & 7) * (nwg >> 3) + (n >> 3)) : n;
  const int bp = w >> 2;
  const int h = w & 3;
  const int b0 = bp * 2;

  // ---- phase 0: Wp-h -> LDS, linear 64KB copy (coalesced 16B/lane) ----
  {
    const f32x4* src = (const f32x4*)(Wp + (long long)h * 32768);  // 65536 B region
    f32x4* dst = (f32x4*)smem;
#pragma unroll
    for (int it = 0; it < 8; ++it) {
      const int idx = tid + it * 512;
      dst[idx] = src[idx];
    }
  }
  __syncthreads();  // barrier 1: Wp-h in LDS

  // ---- GEMM1: 2 x [112x256 bf16] @ [256x128 bf16] -> fp32 acc ----
  const int wm = wv & 3;   // M-group: tiles {2wm, 2wm+1}; wm=3 -> tile 6 only
  const int sh = wv >> 2;  // head-half: 0 -> h0, 1 -> h1
  const int mt0 = wm * 2;
  const bool has1 = (mt0 + 1 < 7);

  f32x4 acc[2][2][4] = {};  // [item][im][nt]
  {
    const bf16* wll = Wl + sh * 16384 + lane * 8;  // frag (sh,kt,nt) + lane
    const bf16* ax0 = xa + (((long long)b0 * 7 + mt0) * 8 * 64 + lane) * 8;
    const bf16* ax1 = ax0 + XA_TILE;
#pragma unroll
    for (int kt = 0; kt < 8; ++kt) {
      bf16x8 a00 = *(const bf16x8*)(ax0 + kt * 512);
      bf16x8 a10 = *(const bf16x8*)(ax1 + kt * 512);
      bf16x8 a01 = {}, a11 = {};
      if (has1) {
        a01 = *(const bf16x8*)(ax0 + 4096 + kt * 512);
        a11 = *(const bf16x8*)(ax1 + 4096 + kt * 512);
      }
      bf16x8 bfr[4];
#pragma unroll
      for (int nt = 0; nt < 4; ++nt)
        bfr[nt] = *(const bf16x8*)(wll + (kt * 4 + nt) * 512);  // ds_read_b128, conflict-free
#pragma unroll
      for (int nt = 0; nt < 4; ++nt) {
        acc[0][0][nt] = __builtin_amdgcn_mfma_f32_16x16x32_bf16(a00, bfr[nt], acc[0][0][nt], 0, 0, 0);
        acc[1][0][nt] = __builtin_amdgcn_mfma_f32_16x16x32_bf16(a10, bfr[nt], acc[1][0][nt], 0, 0, 0);
      }
      if (has1) {
#pragma unroll
        for (int nt = 0; nt < 4; ++nt) {
          acc[0][1][nt] = __builtin_amdgcn_mfma_f32_16x16x32_bf16(a01, bfr[nt], acc[0][1][nt], 0, 0, 0);
          acc[1][1][nt] = __builtin_amdgcn_mfma_f32_16x16x32_bf16(a11, bfr[nt], acc[1][1][nt], 0, 0, 0);
        }
      }
    }
  }
  __syncthreads();  // barrier 2: all Wp LDS reads done; region reusable as S

  // ---- acc -> S_T: S[it][col*SROW + k], k = row (h1, sh=1) or 112+row (h0, sh=0) ----
  {
    const int jb = (sh ? 0 : 112) + (lane >> 4) * 4;
    const int cb = lane & 15;
#pragma unroll
    for (int it2 = 0; it2 < 2; ++it2) {
#pragma unroll
      for (int im = 0; im < 2; ++im) {
        if (mt0 + im < 7) {
          const int j0 = jb + (mt0 + im) * 16;
#pragma unroll
          for (int nt = 0; nt < 4; ++nt) {
            half4 hv;
            hv[0] = (half_t)acc[it2][im][nt][0];
            hv[1] = (half_t)acc[it2][im][nt][1];
            hv[2] = (half_t)acc[it2][im][nt][2];
            hv[3] = (half_t)acc[it2][im][nt][3];
            *(half4*)(&S[it2 * (64 * SROW) + (nt * 16 + cb) * SROW + j0]) = hv;
          }
        }
      }
    }
  }
  __syncthreads();  // barrier 3: S ready

  // ---- GEMM2: wave = (item, mt-pair) -> each wave reads only its G2a frags ----
  const int it2 = wv & 1;
  const int wm2 = wv >> 1;       // 0..3
  const int mt0b = wm2 * 2;      // mt pair {mt0b, mt0b+1}; wm2=3 -> mt 6 only
  const bool has1b = (mt0b + 1 < 7);
  f32x4 a2[2][4] = {};
  {
    const half_t* g2l = G2a + ((long long)(h * 49 + mt0b * 7) * 64 + lane) * 8;
    const half_t* sl = S + it2 * (64 * SROW) + (lane & 15) * SROW + (lane >> 4) * 8;
#pragma unroll
    for (int kt = 0; kt < 7; ++kt) {
      half8 bfr[4];
#pragma unroll
      for (int nt = 0; nt < 4; ++nt)
        bfr[nt] = *(const half8*)(sl + nt * 16 * SROW + kt * 32);
      half8 af0 = *(const half8*)(g2l + (long long)kt * 512);
      half8 af1 = {};
      if (has1b) af1 = *(const half8*)(g2l + (long long)(7 + kt) * 512);
#pragma unroll
      for (int nt = 0; nt < 4; ++nt) {
        a2[0][nt] = __builtin_amdgcn_mfma_f32_16x16x32_f16(af0, bfr[nt], a2[0][nt], 0, 0, 0);
        if (has1b)
          a2[1][nt] = __builtin_amdgcn_mfma_f32_16x16x32_f16(af1, bfr[nt], a2[1][nt], 0, 0, 0);
      }
    }
  }

  // ---- bias + masked store ----
  {
    const int cb = lane & 15;
    const int r0 = (lane >> 4) * 4;
    float bs[4];
#pragma unroll
    for (int nt = 0; nt < 4; ++nt) bs[nt] = bias[h * HC + nt * 16 + cb];
    float* ob = out + (long long)(b0 + it2) * NND * (NH * HC) + h * HC + cb;
#pragma unroll
    for (int im = 0; im < 2; ++im) {
      const int mt = mt0b + im;
      if (mt < 7) {
#pragma unroll
        for (int r = 0; r < 4; ++r) {
          const int row = mt * 16 + r0 + r;
          if (row < NND) {
#pragma unroll
            for (int nt = 0; nt < 4; ++nt)
              ob[(long long)row * (NH * HC) + nt * 16] = a2[im][nt][r] + bs[nt];
          }
        }
      }
    }
  }
}

extern "C" void kernel_launch(void* const* d_in, const int* in_sizes, int n_in,
                              void* d_out, int out_size, void* d_ws, size_t ws_size,
                              hipStream_t stream) {
  const float* x    = (const float*)d_in[0];
  const float* W    = (const float*)d_in[1];
  const float* e    = (const float*)d_in[2];
  const float* bias = (const float*)d_in[3];
  // d_in[4] = rows: unused (fixed pattern: row i owns edges i*K .. i*K+K-1)
  const int* cols   = (const int*)d_in[5];
  float* out        = (float*)d_out;

  int B = in_sizes[0] / (NND * CIN);  // 1024

  bf16* Wp    = (bf16*)((char*)d_ws + WP_OFF);
  half_t* G2d = (half_t*)((char*)d_ws + G2D_OFF);
  half_t* G2a = (half_t*)((char*)d_ws + G2A_OFF);
  bf16* xa    = (bf16*)((char*)d_ws + XA_OFF);

  misc1_kernel<<<68, 256, 0, stream>>>(W, Wp, e, cols, G2d);
  const int Bq = (B + 3) >> 2;
  const int xa_blocks = (Bq * 7 * 8 * 64 + 255) / 256;
  misc2_kernel<<<49 + xa_blocks, 256, 0, stream>>>(G2d, G2a, x, xa, B);

  const int nwg = (B / 2) * NH;
  semgconv_kernel<<<nwg, 512, 0, stream>>>(xa, G2a, Wp, bias, out, nwg);
}

// Round 7
// 230.453 us; speedup vs baseline: 1.1210x; 1.0580x over previous
//
#include <hip/hip_runtime.h>

typedef __bf16 bf16;
typedef bf16 bf16x4 __attribute__((ext_vector_type(4)));
typedef bf16 bf16x8 __attribute__((ext_vector_type(8)));
typedef _Float16 half_t;
typedef half_t half4 __attribute__((ext_vector_type(4)));
typedef half_t half8 __attribute__((ext_vector_type(8)));
typedef float f32x4 __attribute__((ext_vector_type(4)));

#define NND 98      // landmarks
#define KNB 10      // neighbors per node
#define NH 4        // heads
#define CIN 256
#define HC 64
#define KAG 224     // aggregation GEMM K: 0..111 = h1, 112..223 = h0 (diag)
#define SROW 232    // S_T k-stride (224 + 8 pad)
#define XA_TILE (7 * 8 * 64 * 8)  // bf16 elems per batch item in xa

// workspace layout
#define WP_OFF   0
#define WP_BYTES 262144                       // 8*8*4*64*8 bf16
#define G2A_OFF  (WP_OFF + WP_BYTES)
#define G2A_BYTES (NH * 49 * 64 * 8 * 2)      // frag-packed G2, f16
#define XA_OFF   (G2A_OFF + G2A_BYTES)

__device__ __forceinline__ bf16x8 load_a8(const float* p) {
  f32x4 u = *(const f32x4*)p;
  f32x4 v = *(const f32x4*)(p + 4);
  bf16x8 a;
  a[0] = (bf16)u[0]; a[1] = (bf16)u[1]; a[2] = (bf16)u[2]; a[3] = (bf16)u[3];
  a[4] = (bf16)v[0]; a[5] = (bf16)v[1]; a[6] = (bf16)v[2]; a[7] = (bf16)v[3];
  return a;
}

// ---- prep (single dispatch): blocks 0..63 pack Wp; blocks 64..67 build G2a
//      (dense G2 in LDS -> frag pack, no HBM round-trip); blocks 68.. pack xa ----
// Wp[hs][kt(8)][nt(4)][lane(64)][8]: B[k=kt*32+(lane>>4)*8+j][n=nt*16+(lane&15)]
// G2a[h][mt(7)][kt(7)][lane(64)][8]: A[row=mt*16+(l&15)][k=kt*32+(l>>4)*8+j]
// xa[b][mt(7)][kt(8)][lane(64)][8]:  A[row=mt*16+(l&15)][k=kt*32+(l>>4)*8+j], rows>=98 zero
__global__ __launch_bounds__(256) void prep_kernel(const float* __restrict__ W,
                                                   bf16* __restrict__ Wp,
                                                   const float* __restrict__ e,
                                                   const int* __restrict__ cols,
                                                   half_t* __restrict__ G2a,
                                                   const float* __restrict__ x,
                                                   bf16* __restrict__ xa, int B) {
  if (blockIdx.x < 64) {
    int t = blockIdx.x * 256 + threadIdx.x;
    int lane = t & 63;
    int nt = (t >> 6) & 3;
    int kt = (t >> 8) & 7;
    int hs = t >> 11;
    int n = nt * 16 + (lane & 15);
    int kb = kt * 32 + (lane >> 4) * 8;
    const float* src = W + (hs * CIN + kb) * HC + n;
    bf16x8 v;
#pragma unroll
    for (int j = 0; j < 8; ++j) v[j] = (bf16)src[j * HC];
    *(bf16x8*)(Wp + (long long)t * 8) = v;
    return;
  }
  if (blockIdx.x < 68) {
    // one head per block: softmax -> dense G2 (LDS) -> frag-pack -> G2a
    __shared__ __align__(16) half_t g[112 * KAG];  // 50176 B
    const int h = blockIdx.x - 64;
    const int tid = threadIdx.x;
    for (int i = tid; i < 112 * KAG / 2; i += 256) ((unsigned int*)g)[i] = 0u;
    __syncthreads();
    if (tid < NND) {
      const int i = tid;
      const int* cp = cols + i * KNB;
      const float* ep = e + (h * NND + i) * KNB;
      float ev[KNB];
      int cv[KNB];
      float mx = -3.0e38f;
#pragma unroll
      for (int j = 0; j < KNB; ++j) { cv[j] = cp[j]; ev[j] = ep[j]; mx = fmaxf(mx, ev[j]); }
      float s = 0.f;
#pragma unroll
      for (int j = 0; j < KNB; ++j) { ev[j] = __expf(ev[j] - mx); s += ev[j]; }
      const float inv = 1.f / s;
      float dg = 0.f;
#pragma unroll
      for (int j = 0; j < KNB; ++j) {
        float wj = ev[j] * inv;
        if (cv[j] == i) { dg = wj; wj = 0.f; }
        g[i * KAG + cv[j]] = (half_t)wj;
      }
      g[i * KAG + 112 + i] = (half_t)dg;
    }
    __syncthreads();
    // frag pack: 49 (mt,kt) frags x 64 lanes, 16 B each
    for (int u = tid; u < 49 * 64; u += 256) {
      const int lane = u & 63;
      const int q = u >> 6;        // mt*7 + kt
      const int kt = q % 7;
      const int mt = q / 7;
      const int row = mt * 16 + (lane & 15);
      const int k0 = kt * 32 + (lane >> 4) * 8;
      half8 v = *(const half8*)(g + row * KAG + k0);
      *(half8*)(G2a + (((long long)h * 49 + q) * 64 + lane) * 8) = v;
    }
    return;
  }
  // xa pack: 4 items per thread (ILP), coalesced 128B/row reads, coalesced frag writes
  const int Bq = (B + 3) >> 2;
  int u = (blockIdx.x - 68) * 256 + threadIdx.x;
  if (u >= Bq * 7 * 8 * 64) return;
  const int lane = u & 63;
  const int kt = (u >> 6) & 7;
  const int v = u >> 9;
  const int b0 = v / 7;
  const int mt = v - b0 * 7;
  const int row = mt * 16 + (lane & 15);
  const int k0 = kt * 32 + (lane >> 4) * 8;
  bf16x8 a[4];
#pragma unroll
  for (int q = 0; q < 4; ++q) {
    const int b = b0 + Bq * q;
    a[q] = bf16x8{};
    if (b < B && row < NND) a[q] = load_a8(x + ((long long)b * NND + row) * CIN + k0);
  }
#pragma unroll
  for (int q = 0; q < 4; ++q) {
    const int b = b0 + Bq * q;
    if (b < B)
      *(bf16x8*)(xa + ((((long long)b * 7 + mt) * 8 + kt) * 64 + lane) * 8) = a[q];
  }
}

// ---- main: one block per (batch-pair, head). 512 threads = 8 waves. ----
// phase0: stage Wp-h (64KB) -> LDS (linear), with kt=0 A-frags prefetched across it.
// GEMM1 (bf16): B from LDS, A from global xa, 2-deep software pipeline on A.
// S_T (f16) overwrites the Wp LDS region. GEMM2 (f16): A = G2a (global, wave owns
// mt-pair, 2-deep pipeline), B = S from LDS. 3 barriers.
__global__ __launch_bounds__(512, 4) void semgconv_kernel(
    const bf16* __restrict__ xa, const half_t* __restrict__ G2a,
    const bf16* __restrict__ Wp, const float* __restrict__ bias,
    float* __restrict__ out, int nwg) {
  __shared__ __align__(16) unsigned char smem[65536];  // Wp-h stage, then S[2][64*SROW]
  bf16* Wl = (bf16*)smem;
  half_t* S = (half_t*)smem;

  const int tid = threadIdx.x;
  const int lane = tid & 63;
  const int wv = tid >> 6;

  // XCD-chunked swizzle: 4 head-blocks of each pair land on one XCD.
  int n = blockIdx.x;
  int w = ((nwg & 7) == 0) ? ((n & 7) * (nwg >> 3) + (n >> 3)) : n;
  const int bp = w >> 2;
  const int h = w & 3;
  const int b0 = bp * 2;

  const int wm = wv & 3;   // M-group: tiles {2wm, 2wm+1}; wm=3 -> tile 6 only
  const int sh = wv >> 2;  // head-half: 0 -> h0, 1 -> h1
  const int mt0 = wm * 2;
  const bool has1 = (mt0 + 1 < 7);

  // ---- kt=0 A-frag prefetch: issued BEFORE Wp stage, completes during it ----
  const bf16* ax0 = xa + (((long long)b0 * 7 + mt0) * 8 * 64 + lane) * 8;
  const bf16* ax1 = ax0 + XA_TILE;
  bf16x8 a00 = *(const bf16x8*)(ax0);
  bf16x8 a10 = *(const bf16x8*)(ax1);
  bf16x8 a01 = {}, a11 = {};
  if (has1) {
    a01 = *(const bf16x8*)(ax0 + 4096);
    a11 = *(const bf16x8*)(ax1 + 4096);
  }

  // ---- phase 0: Wp-h -> LDS, linear 64KB copy (coalesced 16B/lane) ----
  {
    const f32x4* src = (const f32x4*)(Wp + (long long)h * 32768);
    f32x4* dst = (f32x4*)smem;
#pragma unroll
    for (int it = 0; it < 8; ++it) {
      const int idx = tid + it * 512;
      dst[idx] = src[idx];
    }
  }
  __syncthreads();  // barrier 1: Wp-h in LDS (also drains A prefetch)

  // ---- GEMM1: 2 x [112x256 bf16] @ [256x128 bf16], 2-deep A pipeline ----
  f32x4 acc[2][2][4] = {};  // [item][im][nt]
  {
    const bf16* wll = Wl + sh * 16384 + lane * 8;
#pragma unroll
    for (int kt = 0; kt < 8; ++kt) {
      bf16x8 n00, n10, n01, n11;
      if (kt < 7) {  // issue kt+1 loads before consuming kt
        n00 = *(const bf16x8*)(ax0 + (kt + 1) * 512);
        n10 = *(const bf16x8*)(ax1 + (kt + 1) * 512);
        if (has1) {
          n01 = *(const bf16x8*)(ax0 + 4096 + (kt + 1) * 512);
          n11 = *(const bf16x8*)(ax1 + 4096 + (kt + 1) * 512);
        }
      }
      bf16x8 bfr[4];
#pragma unroll
      for (int nt = 0; nt < 4; ++nt)
        bfr[nt] = *(const bf16x8*)(wll + (kt * 4 + nt) * 512);  // conflict-free b128
#pragma unroll
      for (int nt = 0; nt < 4; ++nt) {
        acc[0][0][nt] = __builtin_amdgcn_mfma_f32_16x16x32_bf16(a00, bfr[nt], acc[0][0][nt], 0, 0, 0);
        acc[1][0][nt] = __builtin_amdgcn_mfma_f32_16x16x32_bf16(a10, bfr[nt], acc[1][0][nt], 0, 0, 0);
      }
      if (has1) {
#pragma unroll
        for (int nt = 0; nt < 4; ++nt) {
          acc[0][1][nt] = __builtin_amdgcn_mfma_f32_16x16x32_bf16(a01, bfr[nt], acc[0][1][nt], 0, 0, 0);
          acc[1][1][nt] = __builtin_amdgcn_mfma_f32_16x16x32_bf16(a11, bfr[nt], acc[1][1][nt], 0, 0, 0);
        }
      }
      a00 = n00; a10 = n10; a01 = n01; a11 = n11;
    }
  }
  __syncthreads();  // barrier 2: all Wp LDS reads done; region reusable as S

  // ---- acc -> S_T: S[it][col*SROW + k], k = row (h1, sh=1) or 112+row (h0, sh=0) ----
  {
    const int jb = (sh ? 0 : 112) + (lane >> 4) * 4;
    const int cb = lane & 15;
#pragma unroll
    for (int it2 = 0; it2 < 2; ++it2) {
#pragma unroll
      for (int im = 0; im < 2; ++im) {
        if (mt0 + im < 7) {
          const int j0 = jb + (mt0 + im) * 16;
#pragma unroll
          for (int nt = 0; nt < 4; ++nt) {
            half4 hv;
            hv[0] = (half_t)acc[it2][im][nt][0];
            hv[1] = (half_t)acc[it2][im][nt][1];
            hv[2] = (half_t)acc[it2][im][nt][2];
            hv[3] = (half_t)acc[it2][im][nt][3];
            *(half4*)(&S[it2 * (64 * SROW) + (nt * 16 + cb) * SROW + j0]) = hv;
          }
        }
      }
    }
  }
  __syncthreads();  // barrier 3: S ready

  // ---- GEMM2: wave = (item, mt-pair), 2-deep G2a pipeline ----
  const int it2 = wv & 1;
  const int wm2 = wv >> 1;
  const int mt0b = wm2 * 2;      // mt pair {mt0b, mt0b+1}; wm2=3 -> mt 6 only
  const bool has1b = (mt0b + 1 < 7);
  f32x4 a2[2][4] = {};
  {
    const half_t* g2l = G2a + ((long long)(h * 49 + mt0b * 7) * 64 + lane) * 8;
    const half_t* sl = S + it2 * (64 * SROW) + (lane & 15) * SROW + (lane >> 4) * 8;
    half8 af0 = *(const half8*)(g2l);
    half8 af1 = {};
    if (has1b) af1 = *(const half8*)(g2l + 7 * 512);
#pragma unroll
    for (int kt = 0; kt < 7; ++kt) {
      half8 n0, n1;
      if (kt < 6) {
        n0 = *(const half8*)(g2l + (long long)(kt + 1) * 512);
        if (has1b) n1 = *(const half8*)(g2l + (long long)(8 + kt) * 512);
      }
      half8 bfr[4];
#pragma unroll
      for (int nt = 0; nt < 4; ++nt)
        bfr[nt] = *(const half8*)(sl + nt * 16 * SROW + kt * 32);
#pragma unroll
      for (int nt = 0; nt < 4; ++nt) {
        a2[0][nt] = __builtin_amdgcn_mfma_f32_16x16x32_f16(af0, bfr[nt], a2[0][nt], 0, 0, 0);
        if (has1b)
          a2[1][nt] = __builtin_amdgcn_mfma_f32_16x16x32_f16(af1, bfr[nt], a2[1][nt], 0, 0, 0);
      }
      af0 = n0; af1 = n1;
    }
  }

  // ---- bias + masked store ----
  {
    const int cb = lane & 15;
    const int r0 = (lane >> 4) * 4;
    float bs[4];
#pragma unroll
    for (int nt = 0; nt < 4; ++nt) bs[nt] = bias[h * HC + nt * 16 + cb];
    float* ob = out + (long long)(b0 + it2) * NND * (NH * HC) + h * HC + cb;
#pragma unroll
    for (int im = 0; im < 2; ++im) {
      const int mt = mt0b + im;
      if (mt < 7) {
#pragma unroll
        for (int r = 0; r < 4; ++r) {
          const int row = mt * 16 + r0 + r;
          if (row < NND) {
#pragma unroll
            for (int nt = 0; nt < 4; ++nt)
              ob[(long long)row * (NH * HC) + nt * 16] = a2[im][nt][r] + bs[nt];
          }
        }
      }
    }
  }
}

extern "C" void kernel_launch(void* const* d_in, const int* in_sizes, int n_in,
                              void* d_out, int out_size, void* d_ws, size_t ws_size,
                              hipStream_t stream) {
  const float* x    = (const float*)d_in[0];
  const float* W    = (const float*)d_in[1];
  const float* e    = (const float*)d_in[2];
  const float* bias = (const float*)d_in[3];
  // d_in[4] = rows: unused (fixed pattern: row i owns edges i*K .. i*K+K-1)
  const int* cols   = (const int*)d_in[5];
  float* out        = (float*)d_out;

  int B = in_sizes[0] / (NND * CIN);  // 1024

  bf16* Wp    = (bf16*)((char*)d_ws + WP_OFF);
  half_t* G2a = (half_t*)((char*)d_ws + G2A_OFF);
  bf16* xa    = (bf16*)((char*)d_ws + XA_OFF);

  const int Bq = (B + 3) >> 2;
  const int xa_blocks = (Bq * 7 * 8 * 64 + 255) / 256;
  prep_kernel<<<68 + xa_blocks, 256, 0, stream>>>(W, Wp, e, cols, G2a, x, xa, B);

  const int nwg = (B / 2) * NH;
  semgconv_kernel<<<nwg, 512, 0, stream>>>(xa, G2a, Wp, bias, out, nwg);
}